// Round 5
// baseline (213.747 us; speedup 1.0000x reference)
//
#include <hip/hip_runtime.h>
#include <hip/hip_bf16.h>

#define NN 10000
#define EE 65536

using short8  = __attribute__((ext_vector_type(8))) short;
using u16x8   = __attribute__((ext_vector_type(8))) unsigned short;
using float4v = __attribute__((ext_vector_type(4))) float;

__device__ __forceinline__ unsigned short f2b(float f){
  union { float f; unsigned int u; } v; v.f = f;
  unsigned int u = v.u;
  unsigned int r = (u + 0x7fff + ((u >> 16) & 1)) >> 16;  // RNE
  return (unsigned short)r;
}

// ---------------- tiled-fragment layout (row-major tile interior) ----------------
// K (A-side) and Bt (B-side) stored as 1024-B tiles = one MFMA wave-fragment:
//   tile index = rowtile*KT32 + k32  (rowtile covers 16 rows, k32 covers 32 k)
//   within tile, elem (row, kk) at short idx  row*32 + kk   (kk linear 0..31)
// => row r's slice of a tile is ONE full 64-B line, written entirely by the
//    block that owns r (no cross-block partial lines -> no write amplification).
// GEMM lane l reads its 16-B granule at (l&15)*32 + (l>>4)*8 — wave covers one
// contiguous 1024-B burst.

// ---------------- prep: zero cnt + permB x2 ----------------

__device__ __forceinline__ void do_permB(int idx, const float* __restrict__ w2,
                                         unsigned short* __restrict__ Bt,
                                         int cin, int s /*log2(KT32)*/, int cb /*log2(cin)*/){
  int tile   = idx >> 9;
  int within = idx & 511;
  int ot  = tile >> s;
  int k32 = tile & ((1<<s)-1);
  int kk   = within & 31;
  int orow = within >> 5;
  int o = ot*16 + orow;
  int k = k32*32 + kk;
  int m = k >> cb;
  int i = k & (cin-1);
  Bt[idx] = f2b(w2[(size_t)m*(cin*64) + i*64 + o]);
}

__global__ __launch_bounds__(256) void k_prep(
    const float* __restrict__ w2a, unsigned short* __restrict__ Bt1,
    const float* __restrict__ w2b, unsigned short* __restrict__ Bt2,
    int* __restrict__ cnt){
  int b = blockIdx.x;
  int t = threadIdx.x;
  if(b < 40){
    int i = b*256 + t;
    if(i < NN) cnt[i] = 0;
  } else if(b < 296){
    do_permB((b-40)*256 + t, w2a, Bt1, 16, 5, 4);
  } else {
    do_permB((b-296)*256 + t, w2b, Bt2, 64, 7, 6);
  }
}

// ---------------- CSR build ----------------

__global__ void k_hist(const int* __restrict__ dst, int* __restrict__ cnt){
  int e = blockIdx.x*256 + threadIdx.x;
  if(e < EE) atomicAdd(&cnt[dst[e]], 1);
}

__global__ __launch_bounds__(1024) void k_scan(const int* __restrict__ cnt, int* __restrict__ offs, int* __restrict__ cursor){
  const int T = 1024, PER = (NN + T - 1)/T; // 10
  int tid = threadIdx.x;
  int base = tid*PER;
  int local[PER];
  int s = 0;
  #pragma unroll
  for(int j=0;j<PER;j++){
    int i = base+j;
    int v = (i<NN)? cnt[i] : 0;
    local[j] = s;
    s += v;
  }
  int lane = tid & 63, wv = tid >> 6;
  int val = s;
  #pragma unroll
  for(int o=1;o<64;o<<=1){
    int u = __shfl_up(val, o, 64);
    if(lane >= o) val += u;
  }
  __shared__ int wsum[16];
  if(lane==63) wsum[wv] = val;
  __syncthreads();
  if(tid==0){
    int acc=0;
    #pragma unroll
    for(int i=0;i<16;i++){ int t2=wsum[i]; wsum[i]=acc; acc+=t2; }
  }
  __syncthreads();
  int thr_excl = wsum[wv] + (val - s);
  #pragma unroll
  for(int j=0;j<PER;j++){
    int i = base+j;
    if(i<NN){ int e = thr_excl + local[j]; offs[i]=e; cursor[i]=e; }
  }
  if(tid == T-1) offs[NN] = thr_excl + s;
}

__global__ void k_scatter(const int* __restrict__ dst, const int* __restrict__ src,
                          int* __restrict__ cursor, int2* __restrict__ elist2){
  int e = blockIdx.x*256 + threadIdx.x;
  if(e < EE){ int p = atomicAdd(&cursor[dst[e]], 1); elist2[p] = make_int2(e, src[e]); }
}

// ---------------- per-dst rank-1 accumulation + inline edge-MLP, cin=16 ----------------

__global__ __launch_bounds__(64) void k_accK1(const float* __restrict__ x,
    const int* __restrict__ offs, const int2* __restrict__ elist2,
    const float* __restrict__ ea, const float* __restrict__ w1, const float* __restrict__ b1,
    unsigned short* __restrict__ K1, float* __restrict__ XS, int v0){
  int v = v0 + blockIdx.x;
  int L = threadIdx.x;
  int cg = L & 3, mg = L >> 2;
  int i0 = cg << 2;
  float w1c0 = w1[L], w1c1 = w1[64+L], w1c2 = w1[128+L], w1c3 = w1[192+L];
  float b1c = b1[L];
  __shared__ float sh[2][64];
  float acc[4][4];
  #pragma unroll
  for(int j=0;j<4;j++)
    #pragma unroll
    for(int c=0;c<4;c++) acc[j][c]=0.f;
  float4 xs = make_float4(0.f,0.f,0.f,0.f);
  int p0 = offs[v], p1 = offs[v+1];
  float4 a_nxt = make_float4(0.f,0.f,0.f,0.f);
  float4 x_nxt = make_float4(0.f,0.f,0.f,0.f);
  if(p0 < p1){
    int2 es = elist2[p0];
    a_nxt = *(const float4*)(ea + (size_t)es.x*4);
    x_nxt = *(const float4*)(x + (size_t)es.y*16 + i0);
  }
  for(int p=p0;p<p1;p++){
    int buf = (p-p0)&1;
    float4 xv = x_nxt;
    float4 av = a_nxt;
    float hv = fmaxf(b1c + av.x*w1c0 + av.y*w1c1 + av.z*w1c2 + av.w*w1c3, 0.f);
    sh[buf][L] = hv;
    __syncthreads();
    if(p+1<p1){
      int2 es = elist2[p+1];
      a_nxt = *(const float4*)(ea + (size_t)es.x*4);
      x_nxt = *(const float4*)(x + (size_t)es.y*16 + i0);
    }
    xs.x += xv.x; xs.y += xv.y; xs.z += xv.z; xs.w += xv.w;
    #pragma unroll
    for(int j=0;j<4;j++){
      float hm = sh[buf][mg + 16*j];
      acc[j][0] += hm*xv.x; acc[j][1] += hm*xv.y;
      acc[j][2] += hm*xv.z; acc[j][3] += hm*xv.w;
    }
  }
  // tiled store: k = m*16 + cg*4 + c -> k32 = m>>1, kk = (m&1)*16 + cg*4 + c
  int r = blockIdx.x;
  int rt = r >> 4, lrow = r & 15;
  #pragma unroll
  for(int j=0;j<4;j++){
    int m = mg + 16*j;
    size_t sidx = ((size_t)(rt*32 + (m>>1)))*512
                + (size_t)lrow*32 + (m&1)*16 + cg*4;
    ushort4 u;
    u.x=f2b(acc[j][0]); u.y=f2b(acc[j][1]); u.z=f2b(acc[j][2]); u.w=f2b(acc[j][3]);
    *(ushort4*)(K1 + sidx) = u;
  }
  if(mg==0) *(float4*)(XS + (size_t)v*64 + i0) = xs;
}

// ---------------- per-dst rank-1 accumulation + inline edge-MLP, cin=64 ----------------

__global__ __launch_bounds__(64) void k_accK2(const float* __restrict__ x1,
    const int* __restrict__ offs, const int2* __restrict__ elist2,
    const float* __restrict__ ea, const float* __restrict__ w1, const float* __restrict__ b1,
    unsigned short* __restrict__ K, float* __restrict__ XS, int v0){
  int v = v0 + blockIdx.x;
  int L = threadIdx.x;
  int cg = L & 7, mg = L >> 3;
  int i0 = cg << 3;
  float w1c0 = w1[L], w1c1 = w1[64+L], w1c2 = w1[128+L], w1c3 = w1[192+L];
  float b1c = b1[L];
  __shared__ float sh[2][64];
  float acc[8][8];
  #pragma unroll
  for(int j=0;j<8;j++)
    #pragma unroll
    for(int c=0;c<8;c++) acc[j][c]=0.f;
  float4 xs0 = make_float4(0.f,0.f,0.f,0.f);
  float4 xs1 = make_float4(0.f,0.f,0.f,0.f);
  int p0 = offs[v], p1 = offs[v+1];
  float4 a_nxt = make_float4(0.f,0.f,0.f,0.f);
  float4 x_nxt0 = make_float4(0.f,0.f,0.f,0.f);
  float4 x_nxt1 = make_float4(0.f,0.f,0.f,0.f);
  if(p0 < p1){
    int2 es = elist2[p0];
    a_nxt = *(const float4*)(ea + (size_t)es.x*4);
    const float* xr = x1 + (size_t)es.y*64 + i0;
    x_nxt0 = *(const float4*)xr;
    x_nxt1 = *(const float4*)(xr+4);
  }
  for(int p=p0;p<p1;p++){
    int buf = (p-p0)&1;
    float4 xv0 = x_nxt0, xv1 = x_nxt1;
    float4 av = a_nxt;
    float hv = fmaxf(b1c + av.x*w1c0 + av.y*w1c1 + av.z*w1c2 + av.w*w1c3, 0.f);
    sh[buf][L] = hv;
    __syncthreads();
    if(p+1<p1){
      int2 es = elist2[p+1];
      a_nxt = *(const float4*)(ea + (size_t)es.x*4);
      const float* xr = x1 + (size_t)es.y*64 + i0;
      x_nxt0 = *(const float4*)xr;
      x_nxt1 = *(const float4*)(xr+4);
    }
    xs0.x += xv0.x; xs0.y += xv0.y; xs0.z += xv0.z; xs0.w += xv0.w;
    xs1.x += xv1.x; xs1.y += xv1.y; xs1.z += xv1.z; xs1.w += xv1.w;
    float4 h4a = *(float4*)&sh[buf][mg*8];
    float4 h4b = *(float4*)&sh[buf][mg*8+4];
    #pragma unroll
    for(int jj=0;jj<2;jj++){
      float4 h4 = jj? h4b : h4a;
      #pragma unroll
      for(int tq=0;tq<4;tq++){
        int j = jj*4+tq;
        float hm = (tq==0)?h4.x:(tq==1)?h4.y:(tq==2)?h4.z:h4.w;
        acc[j][0] += hm*xv0.x; acc[j][1] += hm*xv0.y;
        acc[j][2] += hm*xv0.z; acc[j][3] += hm*xv0.w;
        acc[j][4] += hm*xv1.x; acc[j][5] += hm*xv1.y;
        acc[j][6] += hm*xv1.z; acc[j][7] += hm*xv1.w;
      }
    }
  }
  // tiled store: k = m*64 + cg*8 + c -> k32 = m*2 + (cg>>2), kk = (cg&3)*8 + c
  int r = blockIdx.x;
  int rt = r >> 4, lrow = r & 15;
  #pragma unroll
  for(int j=0;j<8;j++){
    int m = mg*8 + j;
    size_t sidx = ((size_t)(rt*128 + m*2 + (cg>>2)))*512
                + (size_t)lrow*32 + (cg&3)*8;
    u16x8 u;
    #pragma unroll
    for(int c=0;c<8;c++) u[c] = f2b(acc[j][c]);
    *(u16x8*)(K + sidx) = u;
  }
  if(mg==0){
    *(float4*)(XS + (size_t)v*64 + i0)     = xs0;
    *(float4*)(XS + (size_t)v*64 + i0 + 4) = xs1;
  }
}

// ---------------- fused GEMM layer1: MFMA + epilogue -> x1 (no P buffer) ----------------
// 625-ish blocks x 256 thr = 4 waves; block = 16 rows x 64 cols, full K=1024.
// Wave w covers k32 in [w*8, w*8+8). Zero-LDS loads (tiled operands), LDS split-K
// reduce, then fused epilogue: x1 = relu((P + XS*b2)/deg + x@root + bias).

__global__ __launch_bounds__(256) void k_gemmF1(const unsigned short* __restrict__ A,
    const unsigned short* __restrict__ Bt,
    const float* __restrict__ XS, const float* __restrict__ eb,
    const float* __restrict__ xp, const float* __restrict__ rw,
    const float* __restrict__ bw, const int* __restrict__ offs,
    float* __restrict__ x1out, int v0){
  int tid = threadIdx.x;
  int lane = tid & 63;
  int w = tid >> 6;
  int rg = blockIdx.x;
  int lperm = (lane & 15)*32 + (lane >> 4)*8;
  const unsigned short* Ap = A  + (((size_t)rg*32 + w*8) << 9) + lperm;
  const unsigned short* Bp = Bt + (((size_t)w*8) << 9) + lperm;
  size_t bstep = (size_t)32 << 9;

  float4v acc0{}, acc1{}, acc2{}, acc3{};
  short8 a_all[8];
  #pragma unroll
  for(int t=0;t<8;t++) a_all[t] = *(const short8*)(Ap + t*512);

  short8 b0c = *(const short8*)(Bp);
  short8 b1c = *(const short8*)(Bp + bstep);
  short8 b2c = *(const short8*)(Bp + bstep*2);
  short8 b3c = *(const short8*)(Bp + bstep*3);

  #pragma unroll
  for(int t=0;t<8;t++){
    short8 b0n=b0c, b1n=b1c, b2n=b2c, b3n=b3c;
    if(t+1 < 8){
      b0n = *(const short8*)(Bp + (t+1)*512);
      b1n = *(const short8*)(Bp + bstep   + (t+1)*512);
      b2n = *(const short8*)(Bp + bstep*2 + (t+1)*512);
      b3n = *(const short8*)(Bp + bstep*3 + (t+1)*512);
    }
    acc0 = __builtin_amdgcn_mfma_f32_16x16x32_bf16(a_all[t], b0c, acc0, 0,0,0);
    acc1 = __builtin_amdgcn_mfma_f32_16x16x32_bf16(a_all[t], b1c, acc1, 0,0,0);
    acc2 = __builtin_amdgcn_mfma_f32_16x16x32_bf16(a_all[t], b2c, acc2, 0,0,0);
    acc3 = __builtin_amdgcn_mfma_f32_16x16x32_bf16(a_all[t], b3c, acc3, 0,0,0);
    b0c=b0n; b1c=b1n; b2c=b2n; b3c=b3n;
  }

  __shared__ float4v sh4[4][4][64];
  sh4[w][0][lane] = acc0;
  sh4[w][1][lane] = acc1;
  sh4[w][2][lane] = acc2;
  sh4[w][3][lane] = acc3;
  __syncthreads();
  float4v r{};
  #pragma unroll
  for(int w2=0; w2<4; w2++){
    float4v t = sh4[w2][w][lane];
    r[0]+=t[0]; r[1]+=t[1]; r[2]+=t[2]; r[3]+=t[3];
  }

  int lrow = lane & 15, quad = lane >> 4;
  int c = w*16 + lrow;
  int vb = v0 + rg*16 + quad*4;   // global node of reg 0
  float s0=r[0], s1=r[1], s2=r[2], s3=r[3];
  float t0=0.f, t1=0.f, t2=0.f, t3=0.f;
  #pragma unroll
  for(int i=0;i<16;i++){
    float bv = eb[i*64 + c];
    float rv = rw[i*64 + c];
    s0 += XS[(size_t)vb*64       + i]*bv;  t0 += xp[(size_t)vb*16       + i]*rv;
    s1 += XS[(size_t)(vb+1)*64   + i]*bv;  t1 += xp[(size_t)(vb+1)*16   + i]*rv;
    s2 += XS[(size_t)(vb+2)*64   + i]*bv;  t2 += xp[(size_t)(vb+2)*16   + i]*rv;
    s3 += XS[(size_t)(vb+3)*64   + i]*bv;  t3 += xp[(size_t)(vb+3)*16   + i]*rv;
  }
  float bc = bw[c];
  #pragma unroll
  for(int reg=0; reg<4; reg++){
    int v = vb + reg;
    float s = (reg==0)?s0:(reg==1)?s1:(reg==2)?s2:s3;
    float t = (reg==0)?t0:(reg==1)?t1:(reg==2)?t2:t3;
    float dg = fmaxf((float)(offs[v+1]-offs[v]), 1.f);
    x1out[(size_t)v*64 + c] = fmaxf(s/dg + t + bc, 0.f);
  }
}

// ---------------- fused GEMM layer2: MFMA + epilogue + readout -> out ----------------
// block = 16 rows x 64 cols, full K=4096; wave w covers k32 in [w*32, +32).
// A rolling 4-deep prefetch (static names), B 1-deep. After reduce: layer-2
// epilogue (fp32), then fused lin1/lin2 readout via LDS.

__global__ __launch_bounds__(256) void k_gemmF2(const unsigned short* __restrict__ A,
    const unsigned short* __restrict__ Bt,
    const float* __restrict__ XS, const float* __restrict__ eb,
    const float* __restrict__ x1p, const float* __restrict__ rw,
    const float* __restrict__ bw, const int* __restrict__ offs,
    const float* __restrict__ lw1, const float* __restrict__ lb1,
    const float* __restrict__ lw2, const float* __restrict__ lb2,
    float* __restrict__ out, int v0){
  int tid = threadIdx.x;
  int lane = tid & 63;
  int w = tid >> 6;
  int rg = blockIdx.x;
  int lperm = (lane & 15)*32 + (lane >> 4)*8;
  const unsigned short* Ap = A  + (((size_t)rg*128 + w*32) << 9) + lperm;
  const unsigned short* Bp = Bt + (((size_t)w*32) << 9) + lperm;
  size_t bstep = (size_t)128 << 9;

  float4v acc0{}, acc1{}, acc2{}, acc3{};
  short8 aA = *(const short8*)(Ap);
  short8 aB = *(const short8*)(Ap + 512);
  short8 aC = *(const short8*)(Ap + 1024);
  short8 aD = *(const short8*)(Ap + 1536);
  short8 b0c = *(const short8*)(Bp);
  short8 b1c = *(const short8*)(Bp + bstep);
  short8 b2c = *(const short8*)(Bp + bstep*2);
  short8 b3c = *(const short8*)(Bp + bstep*3);

#define GSTEP(AREG, TT) { \
    short8 b0n=b0c, b1n=b1c, b2n=b2c, b3n=b3c; \
    if((TT)+1 < 32){ \
      b0n = *(const short8*)(Bp + ((TT)+1)*512); \
      b1n = *(const short8*)(Bp + bstep   + ((TT)+1)*512); \
      b2n = *(const short8*)(Bp + bstep*2 + ((TT)+1)*512); \
      b3n = *(const short8*)(Bp + bstep*3 + ((TT)+1)*512); \
    } \
    acc0 = __builtin_amdgcn_mfma_f32_16x16x32_bf16(AREG, b0c, acc0, 0,0,0); \
    acc1 = __builtin_amdgcn_mfma_f32_16x16x32_bf16(AREG, b1c, acc1, 0,0,0); \
    acc2 = __builtin_amdgcn_mfma_f32_16x16x32_bf16(AREG, b2c, acc2, 0,0,0); \
    acc3 = __builtin_amdgcn_mfma_f32_16x16x32_bf16(AREG, b3c, acc3, 0,0,0); \
    if((TT)+4 < 32) AREG = *(const short8*)(Ap + ((TT)+4)*512); \
    b0c=b0n; b1c=b1n; b2c=b2n; b3c=b3n; }

  #pragma unroll
  for(int g=0; g<8; g++){
    GSTEP(aA, g*4+0)
    GSTEP(aB, g*4+1)
    GSTEP(aC, g*4+2)
    GSTEP(aD, g*4+3)
  }
#undef GSTEP

  __shared__ float4v sh4[4][4][64];
  sh4[w][0][lane] = acc0;
  sh4[w][1][lane] = acc1;
  sh4[w][2][lane] = acc2;
  sh4[w][3][lane] = acc3;
  __syncthreads();
  float4v r{};
  #pragma unroll
  for(int w2=0; w2<4; w2++){
    float4v t = sh4[w2][w][lane];
    r[0]+=t[0]; r[1]+=t[1]; r[2]+=t[2]; r[3]+=t[3];
  }

  __shared__ float rowsh[16][68];
  __shared__ float hjs[16][8];

  int lrow = lane & 15, quad = lane >> 4;
  int c = w*16 + lrow;
  int rl0 = quad*4;
  int vb = v0 + rg*16 + rl0;
  float s0=r[0], s1=r[1], s2=r[2], s3=r[3];
  float t0=0.f, t1=0.f, t2=0.f, t3=0.f;
  #pragma unroll 8
  for(int i=0;i<64;i++){
    float bv = eb[i*64 + c];
    float rv = rw[i*64 + c];
    s0 += XS[(size_t)vb*64     + i]*bv;  t0 += x1p[(size_t)vb*64     + i]*rv;
    s1 += XS[(size_t)(vb+1)*64 + i]*bv;  t1 += x1p[(size_t)(vb+1)*64 + i]*rv;
    s2 += XS[(size_t)(vb+2)*64 + i]*bv;  t2 += x1p[(size_t)(vb+2)*64 + i]*rv;
    s3 += XS[(size_t)(vb+3)*64 + i]*bv;  t3 += x1p[(size_t)(vb+3)*64 + i]*rv;
  }
  float bc = bw[c];
  #pragma unroll
  for(int reg=0; reg<4; reg++){
    int v = vb + reg;
    float s = (reg==0)?s0:(reg==1)?s1:(reg==2)?s2:s3;
    float t = (reg==0)?t0:(reg==1)?t1:(reg==2)?t2:t3;
    float dg = fmaxf((float)(offs[v+1]-offs[v]), 1.f);
    rowsh[rl0+reg][c] = fmaxf(s/dg + t + bc, 0.f);
  }
  __syncthreads();
  if(tid < 128){
    int n2 = tid >> 3, j = tid & 7;
    float a = lb1[j];
    #pragma unroll
    for(int i=0;i<64;i++) a += rowsh[n2][i]*lw1[i*8+j];
    hjs[n2][j] = fmaxf(a, 0.f)*lw2[j];
  }
  __syncthreads();
  if(tid < 16){
    float s = lb2[0];
    #pragma unroll
    for(int j=0;j<8;j++) s += hjs[tid][j];
    out[v0 + rg*16 + tid] = s;
  }
}

// ---------------- host ----------------

extern "C" void kernel_launch(void* const* d_in, const int* in_sizes, int n_in,
                              void* d_out, int out_size, void* d_ws, size_t ws_size,
                              hipStream_t stream) {
  const float* x      = (const float*)d_in[0];
  const int*   ei     = (const int*)d_in[1];
  const float* ea     = (const float*)d_in[2];
  const float* nn1_w1 = (const float*)d_in[3];
  const float* nn1_b1 = (const float*)d_in[4];
  const float* nn1_w2 = (const float*)d_in[5];
  const float* nn1_b2 = (const float*)d_in[6];
  const float* root1  = (const float*)d_in[7];
  const float* bias1  = (const float*)d_in[8];
  const float* nn2_w1 = (const float*)d_in[9];
  const float* nn2_b1 = (const float*)d_in[10];
  const float* nn2_w2 = (const float*)d_in[11];
  const float* nn2_b2 = (const float*)d_in[12];
  const float* root2  = (const float*)d_in[13];
  const float* bias2  = (const float*)d_in[14];
  const float* lin1_w = (const float*)d_in[15];
  const float* lin1_b = (const float*)d_in[16];
  const float* lin2_w = (const float*)d_in[17];
  const float* lin2_b = (const float*)d_in[18];
  float* out = (float*)d_out;

  const int* srcIdx = ei;
  const int* dstIdx = ei + EE;

  char* w = (char*)d_ws;
  size_t off = 0;
  auto alloc = [&](size_t bytes)->void*{
    void* p = w + off;
    off = (off + bytes + 255) & ~(size_t)255;
    return p;
  };
  int*            cnt    = (int*)           alloc((size_t)NN*4);
  int*            offs   = (int*)           alloc((size_t)(NN+1)*4);
  int*            cursor = (int*)           alloc((size_t)NN*4);
  int2*           elist2 = (int2*)          alloc((size_t)EE*8);
  float*          XS     = (float*)         alloc((size_t)NN*64*4);
  float*          x1     = (float*)         alloc((size_t)NN*64*4);
  unsigned short* Bt1    = (unsigned short*)alloc((size_t)64*1024*2);
  unsigned short* Bt2    = (unsigned short*)alloc((size_t)64*4096*2);
  size_t fixedBytes = off;
  size_t R = (ws_size > fixedBytes) ? (ws_size - fixedBytes) : 0;

  // K2 tiled buffer: (NN/16) * 128 tiles * 1024 B = 81.92 MB (K1 fits inside: 20.5 MB)
  size_t needSingle = (size_t)(NN/16)*128*1024;
  bool single = (R >= needSingle + 4096);

  k_prep   <<<1320, 256, 0, stream>>>(nn1_w2, Bt1, nn2_w2, Bt2, cnt);
  k_hist   <<<(EE+255)/256, 256, 0, stream>>>(dstIdx, cnt);
  k_scan   <<<1, 1024, 0, stream>>>(cnt, offs, cursor);
  k_scatter<<<(EE+255)/256, 256, 0, stream>>>(dstIdx, srcIdx, cursor, elist2);

  if(single){
    unsigned short* Kbuf = (unsigned short*)(w + off);

    k_accK1 <<<NN, 64, 0, stream>>>(x, offs, elist2, ea, nn1_w1, nn1_b1, Kbuf, XS, 0);
    k_gemmF1<<<NN/16, 256, 0, stream>>>(Kbuf, Bt1, XS, nn1_b2, x, root1, bias1, offs, x1, 0);
    k_accK2 <<<NN, 64, 0, stream>>>(x1, offs, elist2, ea, nn2_w1, nn2_b1, Kbuf, XS, 0);
    k_gemmF2<<<NN/16, 256, 0, stream>>>(Kbuf, Bt2, XS, nn2_b2, x1, root2, bias2, offs,
                                        lin1_w, lin1_b, lin2_w, lin2_b, out, 0);
  } else {
    // chunked fallback: per-16-rows bytes = 2048 (layer1) / 8192 (layer2)
    long long C2 = (long long)(R / 8192);
    long long C1 = (long long)(R / 2048);
    if(C2 > NN) C2 = NN; if(C1 > NN) C1 = NN;
    C2 &= ~63LL; C1 &= ~63LL;
    if(C2 < 128) C2 = 128; if(C1 < 128) C1 = 128;
    unsigned short* Kbuf = (unsigned short*)(w + off);
    for(long long v0=0; v0<NN; v0+=C1){
      int rows = (int)((NN - v0 < C1) ? (NN - v0) : C1);
      k_accK1 <<<rows, 64, 0, stream>>>(x, offs, elist2, ea, nn1_w1, nn1_b1, Kbuf, XS, (int)v0);
      k_gemmF1<<<rows/16, 256, 0, stream>>>(Kbuf, Bt1, XS, nn1_b2, x, root1, bias1, offs, x1, (int)v0);
    }
    for(long long v0=0; v0<NN; v0+=C2){
      int rows = (int)((NN - v0 < C2) ? (NN - v0) : C2);
      k_accK2 <<<rows, 64, 0, stream>>>(x1, offs, elist2, ea, nn2_w1, nn2_b1, Kbuf, XS, (int)v0);
      k_gemmF2<<<rows/16, 256, 0, stream>>>(Kbuf, Bt2, XS, nn2_b2, x1, root2, bias2, offs,
                                            lin1_w, lin1_b, lin2_w, lin2_b, out, (int)v0);
    }
  }
}

// Round 6
// 212.598 us; speedup vs baseline: 1.0054x; 1.0054x over previous
//
#include <hip/hip_runtime.h>
#include <hip/hip_bf16.h>

#define NN 10000
#define EE 65536

using short8  = __attribute__((ext_vector_type(8))) short;
using u16x8   = __attribute__((ext_vector_type(8))) unsigned short;
using float4v = __attribute__((ext_vector_type(4))) float;

__device__ __forceinline__ unsigned short f2b(float f){
  union { float f; unsigned int u; } v; v.f = f;
  unsigned int u = v.u;
  unsigned int r = (u + 0x7fff + ((u >> 16) & 1)) >> 16;  // RNE
  return (unsigned short)r;
}

// non-temporal (no L2-allocate) load of a 16-B fragment granule: A is written
// once by accK and read exactly once here -> keep it OUT of L2 so Bt stays resident.
__device__ __forceinline__ short8 ntload(const unsigned short* p){
  return __builtin_nontemporal_load((const short8*)p);
}

// ---------------- tiled-fragment layout (row-major tile interior) ----------------
// K (A-side) and Bt (B-side) stored as 1024-B tiles = one MFMA wave-fragment:
//   tile index = rowtile*KT32 + k32  (rowtile covers 16 rows, k32 covers 32 k)
//   within tile, elem (row, kk) at short idx  row*32 + kk
// => row r's slice of a tile is ONE full 64-B line owned by r's producer block.
// GEMM lane l reads its 16-B granule at (l&15)*32 + (l>>4)*8 — wave covers one
// contiguous 1024-B burst.

// ---------------- prep: zero cnt + permB x2 ----------------

__device__ __forceinline__ void do_permB(int idx, const float* __restrict__ w2,
                                         unsigned short* __restrict__ Bt,
                                         int cin, int s /*log2(KT32)*/, int cb /*log2(cin)*/){
  int tile   = idx >> 9;
  int within = idx & 511;
  int ot  = tile >> s;
  int k32 = tile & ((1<<s)-1);
  int kk   = within & 31;
  int orow = within >> 5;
  int o = ot*16 + orow;
  int k = k32*32 + kk;
  int m = k >> cb;
  int i = k & (cin-1);
  Bt[idx] = f2b(w2[(size_t)m*(cin*64) + i*64 + o]);
}

__global__ __launch_bounds__(256) void k_prep(
    const float* __restrict__ w2a, unsigned short* __restrict__ Bt1,
    const float* __restrict__ w2b, unsigned short* __restrict__ Bt2,
    int* __restrict__ cnt){
  int b = blockIdx.x;
  int t = threadIdx.x;
  if(b < 40){
    int i = b*256 + t;
    if(i < NN) cnt[i] = 0;
  } else if(b < 296){
    do_permB((b-40)*256 + t, w2a, Bt1, 16, 5, 4);
  } else {
    do_permB((b-296)*256 + t, w2b, Bt2, 64, 7, 6);
  }
}

// ---------------- CSR build ----------------

__global__ void k_hist(const int* __restrict__ dst, int* __restrict__ cnt){
  int e = blockIdx.x*256 + threadIdx.x;
  if(e < EE) atomicAdd(&cnt[dst[e]], 1);
}

__global__ __launch_bounds__(1024) void k_scan(const int* __restrict__ cnt, int* __restrict__ offs, int* __restrict__ cursor){
  const int T = 1024, PER = (NN + T - 1)/T; // 10
  int tid = threadIdx.x;
  int base = tid*PER;
  int local[PER];
  int s = 0;
  #pragma unroll
  for(int j=0;j<PER;j++){
    int i = base+j;
    int v = (i<NN)? cnt[i] : 0;
    local[j] = s;
    s += v;
  }
  int lane = tid & 63, wv = tid >> 6;
  int val = s;
  #pragma unroll
  for(int o=1;o<64;o<<=1){
    int u = __shfl_up(val, o, 64);
    if(lane >= o) val += u;
  }
  __shared__ int wsum[16];
  if(lane==63) wsum[wv] = val;
  __syncthreads();
  if(tid==0){
    int acc=0;
    #pragma unroll
    for(int i=0;i<16;i++){ int t2=wsum[i]; wsum[i]=acc; acc+=t2; }
  }
  __syncthreads();
  int thr_excl = wsum[wv] + (val - s);
  #pragma unroll
  for(int j=0;j<PER;j++){
    int i = base+j;
    if(i<NN){ int e = thr_excl + local[j]; offs[i]=e; cursor[i]=e; }
  }
  if(tid == T-1) offs[NN] = thr_excl + s;
}

__global__ void k_scatter(const int* __restrict__ dst, const int* __restrict__ src,
                          int* __restrict__ cursor, int2* __restrict__ elist2){
  int e = blockIdx.x*256 + threadIdx.x;
  if(e < EE){ int p = atomicAdd(&cursor[dst[e]], 1); elist2[p] = make_int2(e, src[e]); }
}

// ---------------- per-dst rank-1 accumulation + inline edge-MLP, cin=16 ----------------

__global__ __launch_bounds__(64) void k_accK1(const float* __restrict__ x,
    const int* __restrict__ offs, const int2* __restrict__ elist2,
    const float* __restrict__ ea, const float* __restrict__ w1, const float* __restrict__ b1,
    unsigned short* __restrict__ K1, float* __restrict__ XS, int v0){
  int v = v0 + blockIdx.x;
  int L = threadIdx.x;
  int cg = L & 3, mg = L >> 2;
  int i0 = cg << 2;
  float w1c0 = w1[L], w1c1 = w1[64+L], w1c2 = w1[128+L], w1c3 = w1[192+L];
  float b1c = b1[L];
  __shared__ float sh[2][64];
  float acc[4][4];
  #pragma unroll
  for(int j=0;j<4;j++)
    #pragma unroll
    for(int c=0;c<4;c++) acc[j][c]=0.f;
  float4 xs = make_float4(0.f,0.f,0.f,0.f);
  int p0 = offs[v], p1 = offs[v+1];
  float4 a_nxt = make_float4(0.f,0.f,0.f,0.f);
  float4 x_nxt = make_float4(0.f,0.f,0.f,0.f);
  if(p0 < p1){
    int2 es = elist2[p0];
    a_nxt = *(const float4*)(ea + (size_t)es.x*4);
    x_nxt = *(const float4*)(x + (size_t)es.y*16 + i0);
  }
  for(int p=p0;p<p1;p++){
    int buf = (p-p0)&1;
    float4 xv = x_nxt;
    float4 av = a_nxt;
    float hv = fmaxf(b1c + av.x*w1c0 + av.y*w1c1 + av.z*w1c2 + av.w*w1c3, 0.f);
    sh[buf][L] = hv;
    __syncthreads();
    if(p+1<p1){
      int2 es = elist2[p+1];
      a_nxt = *(const float4*)(ea + (size_t)es.x*4);
      x_nxt = *(const float4*)(x + (size_t)es.y*16 + i0);
    }
    xs.x += xv.x; xs.y += xv.y; xs.z += xv.z; xs.w += xv.w;
    #pragma unroll
    for(int j=0;j<4;j++){
      float hm = sh[buf][mg + 16*j];
      acc[j][0] += hm*xv.x; acc[j][1] += hm*xv.y;
      acc[j][2] += hm*xv.z; acc[j][3] += hm*xv.w;
    }
  }
  int r = blockIdx.x;
  int rt = r >> 4, lrow = r & 15;
  #pragma unroll
  for(int j=0;j<4;j++){
    int m = mg + 16*j;
    size_t sidx = ((size_t)(rt*32 + (m>>1)))*512
                + (size_t)lrow*32 + (m&1)*16 + cg*4;
    ushort4 u;
    u.x=f2b(acc[j][0]); u.y=f2b(acc[j][1]); u.z=f2b(acc[j][2]); u.w=f2b(acc[j][3]);
    *(ushort4*)(K1 + sidx) = u;
  }
  if(mg==0) *(float4*)(XS + (size_t)v*64 + i0) = xs;
}

// ---------------- per-dst rank-1 accumulation + inline edge-MLP, cin=64 ----------------

__global__ __launch_bounds__(64) void k_accK2(const float* __restrict__ x1,
    const int* __restrict__ offs, const int2* __restrict__ elist2,
    const float* __restrict__ ea, const float* __restrict__ w1, const float* __restrict__ b1,
    unsigned short* __restrict__ K, float* __restrict__ XS, int v0){
  int v = v0 + blockIdx.x;
  int L = threadIdx.x;
  int cg = L & 7, mg = L >> 3;
  int i0 = cg << 3;
  float w1c0 = w1[L], w1c1 = w1[64+L], w1c2 = w1[128+L], w1c3 = w1[192+L];
  float b1c = b1[L];
  __shared__ float sh[2][64];
  float acc[8][8];
  #pragma unroll
  for(int j=0;j<8;j++)
    #pragma unroll
    for(int c=0;c<8;c++) acc[j][c]=0.f;
  float4 xs0 = make_float4(0.f,0.f,0.f,0.f);
  float4 xs1 = make_float4(0.f,0.f,0.f,0.f);
  int p0 = offs[v], p1 = offs[v+1];
  float4 a_nxt = make_float4(0.f,0.f,0.f,0.f);
  float4 x_nxt0 = make_float4(0.f,0.f,0.f,0.f);
  float4 x_nxt1 = make_float4(0.f,0.f,0.f,0.f);
  if(p0 < p1){
    int2 es = elist2[p0];
    a_nxt = *(const float4*)(ea + (size_t)es.x*4);
    const float* xr = x1 + (size_t)es.y*64 + i0;
    x_nxt0 = *(const float4*)xr;
    x_nxt1 = *(const float4*)(xr+4);
  }
  for(int p=p0;p<p1;p++){
    int buf = (p-p0)&1;
    float4 xv0 = x_nxt0, xv1 = x_nxt1;
    float4 av = a_nxt;
    float hv = fmaxf(b1c + av.x*w1c0 + av.y*w1c1 + av.z*w1c2 + av.w*w1c3, 0.f);
    sh[buf][L] = hv;
    __syncthreads();
    if(p+1<p1){
      int2 es = elist2[p+1];
      a_nxt = *(const float4*)(ea + (size_t)es.x*4);
      const float* xr = x1 + (size_t)es.y*64 + i0;
      x_nxt0 = *(const float4*)xr;
      x_nxt1 = *(const float4*)(xr+4);
    }
    xs0.x += xv0.x; xs0.y += xv0.y; xs0.z += xv0.z; xs0.w += xv0.w;
    xs1.x += xv1.x; xs1.y += xv1.y; xs1.z += xv1.z; xs1.w += xv1.w;
    float4 h4a = *(float4*)&sh[buf][mg*8];
    float4 h4b = *(float4*)&sh[buf][mg*8+4];
    #pragma unroll
    for(int jj=0;jj<2;jj++){
      float4 h4 = jj? h4b : h4a;
      #pragma unroll
      for(int tq=0;tq<4;tq++){
        int j = jj*4+tq;
        float hm = (tq==0)?h4.x:(tq==1)?h4.y:(tq==2)?h4.z:h4.w;
        acc[j][0] += hm*xv0.x; acc[j][1] += hm*xv0.y;
        acc[j][2] += hm*xv0.z; acc[j][3] += hm*xv0.w;
        acc[j][4] += hm*xv1.x; acc[j][5] += hm*xv1.y;
        acc[j][6] += hm*xv1.z; acc[j][7] += hm*xv1.w;
      }
    }
  }
  int r = blockIdx.x;
  int rt = r >> 4, lrow = r & 15;
  #pragma unroll
  for(int j=0;j<8;j++){
    int m = mg*8 + j;
    size_t sidx = ((size_t)(rt*128 + m*2 + (cg>>2)))*512
                + (size_t)lrow*32 + (cg&3)*8;
    u16x8 u;
    #pragma unroll
    for(int c=0;c<8;c++) u[c] = f2b(acc[j][c]);
    *(u16x8*)(K + sidx) = u;
  }
  if(mg==0){
    *(float4*)(XS + (size_t)v*64 + i0)     = xs0;
    *(float4*)(XS + (size_t)v*64 + i0 + 4) = xs1;
  }
}

// ---------------- fused GEMM layer1: MFMA + epilogue -> x1 ----------------
// 4 waves; block = 16 rows x 64 cols, full K=1024; wave w: k32 in [w*8,+8).
// A loads non-temporal (read-once stream, keep L2 for Bt); B 2-deep prefetch.

__global__ __launch_bounds__(256) void k_gemmF1(const unsigned short* __restrict__ A,
    const unsigned short* __restrict__ Bt,
    const float* __restrict__ XS, const float* __restrict__ eb,
    const float* __restrict__ xp, const float* __restrict__ rw,
    const float* __restrict__ bw, const int* __restrict__ offs,
    float* __restrict__ x1out, int v0){
  int tid = threadIdx.x;
  int lane = tid & 63;
  int w = tid >> 6;
  int rg = blockIdx.x;
  int lperm = (lane & 15)*32 + (lane >> 4)*8;
  const unsigned short* Ap = A  + (((size_t)rg*32 + w*8) << 9) + lperm;
  const unsigned short* Bp = Bt + (((size_t)w*8) << 9) + lperm;
  size_t bstep = (size_t)32 << 9;

  float4v acc0{}, acc1{}, acc2{}, acc3{};
  short8 a_all[8];
  #pragma unroll
  for(int t=0;t<8;t++) a_all[t] = ntload(Ap + t*512);

  short8 bb[2][4];
  #pragma unroll
  for(int ph=0; ph<2; ph++)
    #pragma unroll
    for(int cc=0; cc<4; cc++)
      bb[ph][cc] = *(const short8*)(Bp + bstep*cc + ph*512);

  #pragma unroll
  for(int t=0;t<8;t++){
    short8 a = a_all[t];
    acc0 = __builtin_amdgcn_mfma_f32_16x16x32_bf16(a, bb[t&1][0], acc0, 0,0,0);
    acc1 = __builtin_amdgcn_mfma_f32_16x16x32_bf16(a, bb[t&1][1], acc1, 0,0,0);
    acc2 = __builtin_amdgcn_mfma_f32_16x16x32_bf16(a, bb[t&1][2], acc2, 0,0,0);
    acc3 = __builtin_amdgcn_mfma_f32_16x16x32_bf16(a, bb[t&1][3], acc3, 0,0,0);
    if(t+2 < 8){
      #pragma unroll
      for(int cc=0; cc<4; cc++)
        bb[t&1][cc] = *(const short8*)(Bp + bstep*cc + (t+2)*512);
    }
  }

  __shared__ float4v sh4[4][4][64];
  sh4[w][0][lane] = acc0;
  sh4[w][1][lane] = acc1;
  sh4[w][2][lane] = acc2;
  sh4[w][3][lane] = acc3;
  __syncthreads();
  float4v r{};
  #pragma unroll
  for(int w2=0; w2<4; w2++){
    float4v t = sh4[w2][w][lane];
    r[0]+=t[0]; r[1]+=t[1]; r[2]+=t[2]; r[3]+=t[3];
  }

  int lrow = lane & 15, quad = lane >> 4;
  int c = w*16 + lrow;
  int vb = v0 + rg*16 + quad*4;
  float s0=r[0], s1=r[1], s2=r[2], s3=r[3];
  float t0=0.f, t1=0.f, t2=0.f, t3=0.f;
  #pragma unroll
  for(int i=0;i<16;i++){
    float bv = eb[i*64 + c];
    float rv = rw[i*64 + c];
    s0 += XS[(size_t)vb*64       + i]*bv;  t0 += xp[(size_t)vb*16       + i]*rv;
    s1 += XS[(size_t)(vb+1)*64   + i]*bv;  t1 += xp[(size_t)(vb+1)*16   + i]*rv;
    s2 += XS[(size_t)(vb+2)*64   + i]*bv;  t2 += xp[(size_t)(vb+2)*16   + i]*rv;
    s3 += XS[(size_t)(vb+3)*64   + i]*bv;  t3 += xp[(size_t)(vb+3)*16   + i]*rv;
  }
  float bc = bw[c];
  #pragma unroll
  for(int reg=0; reg<4; reg++){
    int v = vb + reg;
    float s = (reg==0)?s0:(reg==1)?s1:(reg==2)?s2:s3;
    float t = (reg==0)?t0:(reg==1)?t1:(reg==2)?t2:t3;
    float dg = fmaxf((float)(offs[v+1]-offs[v]), 1.f);
    x1out[(size_t)v*64 + c] = fmaxf(s/dg + t + bc, 0.f);
  }
}

// ---------------- fused GEMM layer2: MFMA + epilogue + readout -> out ----------------
// block = 16 rows x 64 cols, full K=4096; wave w: k32 in [w*32,+32).
// A non-temporal 4-deep; B (L2-resident) 2-deep. Static array indices (full unroll).

__global__ __launch_bounds__(256) void k_gemmF2(const unsigned short* __restrict__ A,
    const unsigned short* __restrict__ Bt,
    const float* __restrict__ XS, const float* __restrict__ eb,
    const float* __restrict__ x1p, const float* __restrict__ rw,
    const float* __restrict__ bw, const int* __restrict__ offs,
    const float* __restrict__ lw1, const float* __restrict__ lb1,
    const float* __restrict__ lw2, const float* __restrict__ lb2,
    float* __restrict__ out, int v0){
  int tid = threadIdx.x;
  int lane = tid & 63;
  int w = tid >> 6;
  int rg = blockIdx.x;
  int lperm = (lane & 15)*32 + (lane >> 4)*8;
  const unsigned short* Ap = A  + (((size_t)rg*128 + w*32) << 9) + lperm;
  const unsigned short* Bp = Bt + (((size_t)w*32) << 9) + lperm;
  size_t bstep = (size_t)128 << 9;

  float4v acc0{}, acc1{}, acc2{}, acc3{};
  short8 ab[4];
  #pragma unroll
  for(int t=0;t<4;t++) ab[t] = ntload(Ap + t*512);

  short8 bb[2][4];
  #pragma unroll
  for(int ph=0; ph<2; ph++)
    #pragma unroll
    for(int cc=0; cc<4; cc++)
      bb[ph][cc] = *(const short8*)(Bp + bstep*cc + ph*512);

  #pragma unroll
  for(int t=0;t<32;t++){
    short8 a = ab[t&3];
    acc0 = __builtin_amdgcn_mfma_f32_16x16x32_bf16(a, bb[t&1][0], acc0, 0,0,0);
    acc1 = __builtin_amdgcn_mfma_f32_16x16x32_bf16(a, bb[t&1][1], acc1, 0,0,0);
    acc2 = __builtin_amdgcn_mfma_f32_16x16x32_bf16(a, bb[t&1][2], acc2, 0,0,0);
    acc3 = __builtin_amdgcn_mfma_f32_16x16x32_bf16(a, bb[t&1][3], acc3, 0,0,0);
    if(t+2 < 32){
      #pragma unroll
      for(int cc=0; cc<4; cc++)
        bb[t&1][cc] = *(const short8*)(Bp + bstep*cc + (t+2)*512);
    }
    if(t+4 < 32) ab[t&3] = ntload(Ap + (t+4)*512);
  }

  __shared__ float4v sh4[4][4][64];
  sh4[w][0][lane] = acc0;
  sh4[w][1][lane] = acc1;
  sh4[w][2][lane] = acc2;
  sh4[w][3][lane] = acc3;
  __syncthreads();
  float4v r{};
  #pragma unroll
  for(int w2=0; w2<4; w2++){
    float4v t = sh4[w2][w][lane];
    r[0]+=t[0]; r[1]+=t[1]; r[2]+=t[2]; r[3]+=t[3];
  }

  __shared__ float rowsh[16][68];
  __shared__ float hjs[16][8];

  int lrow = lane & 15, quad = lane >> 4;
  int c = w*16 + lrow;
  int rl0 = quad*4;
  int vb = v0 + rg*16 + rl0;
  float s0=r[0], s1=r[1], s2=r[2], s3=r[3];
  float t0=0.f, t1=0.f, t2=0.f, t3=0.f;
  #pragma unroll 8
  for(int i=0;i<64;i++){
    float bv = eb[i*64 + c];
    float rv = rw[i*64 + c];
    s0 += XS[(size_t)vb*64     + i]*bv;  t0 += x1p[(size_t)vb*64     + i]*rv;
    s1 += XS[(size_t)(vb+1)*64 + i]*bv;  t1 += x1p[(size_t)(vb+1)*64 + i]*rv;
    s2 += XS[(size_t)(vb+2)*64 + i]*bv;  t2 += x1p[(size_t)(vb+2)*64 + i]*rv;
    s3 += XS[(size_t)(vb+3)*64 + i]*bv;  t3 += x1p[(size_t)(vb+3)*64 + i]*rv;
  }
  float bc = bw[c];
  #pragma unroll
  for(int reg=0; reg<4; reg++){
    int v = vb + reg;
    float s = (reg==0)?s0:(reg==1)?s1:(reg==2)?s2:s3;
    float t = (reg==0)?t0:(reg==1)?t1:(reg==2)?t2:t3;
    float dg = fmaxf((float)(offs[v+1]-offs[v]), 1.f);
    rowsh[rl0+reg][c] = fmaxf(s/dg + t + bc, 0.f);
  }
  __syncthreads();
  if(tid < 128){
    int n2 = tid >> 3, j = tid & 7;
    float a = lb1[j];
    #pragma unroll
    for(int i=0;i<64;i++) a += rowsh[n2][i]*lw1[i*8+j];
    hjs[n2][j] = fmaxf(a, 0.f)*lw2[j];
  }
  __syncthreads();
  if(tid < 16){
    float s = lb2[0];
    #pragma unroll
    for(int j=0;j<8;j++) s += hjs[tid][j];
    out[v0 + rg*16 + tid] = s;
  }
}

// ---------------- host ----------------

extern "C" void kernel_launch(void* const* d_in, const int* in_sizes, int n_in,
                              void* d_out, int out_size, void* d_ws, size_t ws_size,
                              hipStream_t stream) {
  const float* x      = (const float*)d_in[0];
  const int*   ei     = (const int*)d_in[1];
  const float* ea     = (const float*)d_in[2];
  const float* nn1_w1 = (const float*)d_in[3];
  const float* nn1_b1 = (const float*)d_in[4];
  const float* nn1_w2 = (const float*)d_in[5];
  const float* nn1_b2 = (const float*)d_in[6];
  const float* root1  = (const float*)d_in[7];
  const float* bias1  = (const float*)d_in[8];
  const float* nn2_w1 = (const float*)d_in[9];
  const float* nn2_b1 = (const float*)d_in[10];
  const float* nn2_w2 = (const float*)d_in[11];
  const float* nn2_b2 = (const float*)d_in[12];
  const float* root2  = (const float*)d_in[13];
  const float* bias2  = (const float*)d_in[14];
  const float* lin1_w = (const float*)d_in[15];
  const float* lin1_b = (const float*)d_in[16];
  const float* lin2_w = (const float*)d_in[17];
  const float* lin2_b = (const float*)d_in[18];
  float* out = (float*)d_out;

  const int* srcIdx = ei;
  const int* dstIdx = ei + EE;

  char* w = (char*)d_ws;
  size_t off = 0;
  auto alloc = [&](size_t bytes)->void*{
    void* p = w + off;
    off = (off + bytes + 255) & ~(size_t)255;
    return p;
  };
  int*            cnt    = (int*)           alloc((size_t)NN*4);
  int*            offs   = (int*)           alloc((size_t)(NN+1)*4);
  int*            cursor = (int*)           alloc((size_t)NN*4);
  int2*           elist2 = (int2*)          alloc((size_t)EE*8);
  float*          XS     = (float*)         alloc((size_t)NN*64*4);
  float*          x1     = (float*)         alloc((size_t)NN*64*4);
  unsigned short* Bt1    = (unsigned short*)alloc((size_t)64*1024*2);
  unsigned short* Bt2    = (unsigned short*)alloc((size_t)64*4096*2);
  size_t fixedBytes = off;
  size_t R = (ws_size > fixedBytes) ? (ws_size - fixedBytes) : 0;

  // K2 tiled buffer: (NN/16) * 128 tiles * 1024 B = 81.92 MB (K1 fits inside)
  size_t needSingle = (size_t)(NN/16)*128*1024;
  bool single = (R >= needSingle + 4096);

  k_prep   <<<1320, 256, 0, stream>>>(nn1_w2, Bt1, nn2_w2, Bt2, cnt);
  k_hist   <<<(EE+255)/256, 256, 0, stream>>>(dstIdx, cnt);
  k_scan   <<<1, 1024, 0, stream>>>(cnt, offs, cursor);
  k_scatter<<<(EE+255)/256, 256, 0, stream>>>(dstIdx, srcIdx, cursor, elist2);

  if(single){
    unsigned short* Kbuf = (unsigned short*)(w + off);

    k_accK1 <<<NN, 64, 0, stream>>>(x, offs, elist2, ea, nn1_w1, nn1_b1, Kbuf, XS, 0);
    k_gemmF1<<<NN/16, 256, 0, stream>>>(Kbuf, Bt1, XS, nn1_b2, x, root1, bias1, offs, x1, 0);
    k_accK2 <<<NN, 64, 0, stream>>>(x1, offs, elist2, ea, nn2_w1, nn2_b1, Kbuf, XS, 0);
    k_gemmF2<<<NN/16, 256, 0, stream>>>(Kbuf, Bt2, XS, nn2_b2, x1, root2, bias2, offs,
                                        lin1_w, lin1_b, lin2_w, lin2_b, out, 0);
  } else {
    long long C2 = (long long)(R / 8192);
    long long C1 = (long long)(R / 2048);
    if(C2 > NN) C2 = NN; if(C1 > NN) C1 = NN;
    C2 &= ~63LL; C1 &= ~63LL;
    if(C2 < 128) C2 = 128; if(C1 < 128) C1 = 128;
    unsigned short* Kbuf = (unsigned short*)(w + off);
    for(long long v0=0; v0<NN; v0+=C1){
      int rows = (int)((NN - v0 < C1) ? (NN - v0) : C1);
      k_accK1 <<<rows, 64, 0, stream>>>(x, offs, elist2, ea, nn1_w1, nn1_b1, Kbuf, XS, (int)v0);
      k_gemmF1<<<rows/16, 256, 0, stream>>>(Kbuf, Bt1, XS, nn1_b2, x, root1, bias1, offs, x1, (int)v0);
    }
    for(long long v0=0; v0<NN; v0+=C2){
      int rows = (int)((NN - v0 < C2) ? (NN - v0) : C2);
      k_accK2 <<<rows, 64, 0, stream>>>(x1, offs, elist2, ea, nn2_w1, nn2_b1, Kbuf, XS, (int)v0);
      k_gemmF2<<<rows/16, 256, 0, stream>>>(Kbuf, Bt2, XS, nn2_b2, x1, root2, bias2, offs,
                                            lin1_w, lin1_b, lin2_w, lin2_b, out, (int)v0);
    }
  }
}

// Round 7
// 204.777 us; speedup vs baseline: 1.0438x; 1.0382x over previous
//
#include <hip/hip_runtime.h>
#include <hip/hip_bf16.h>

#define NN 10000
#define EE 65536

using short8  = __attribute__((ext_vector_type(8))) short;
using u16x8   = __attribute__((ext_vector_type(8))) unsigned short;
using float4v = __attribute__((ext_vector_type(4))) float;

__device__ __forceinline__ unsigned short f2b(float f){
  union { float f; unsigned int u; } v; v.f = f;
  unsigned int u = v.u;
  unsigned int r = (u + 0x7fff + ((u >> 16) & 1)) >> 16;  // RNE
  return (unsigned short)r;
}

__device__ __forceinline__ short8 ntload(const unsigned short* p){
  return __builtin_nontemporal_load((const short8*)p);
}

// ---------------- tiled-fragment layout (row-major tile interior) ----------------
// K (A-side) and Bt (B-side) stored as 1024-B tiles = one MFMA wave-fragment:
//   tile index = rowtile*KT32 + k32 ; within tile, elem (row,kk) at short row*32+kk.
// GEMM lane l reads its granule at (l&15)*32 + (l>>4)*8 shorts.

// ---------------- prep: zero cnt + permB x2 ----------------

__device__ __forceinline__ void do_permB(int idx, const float* __restrict__ w2,
                                         unsigned short* __restrict__ Bt,
                                         int cin, int s /*log2(KT32)*/, int cb /*log2(cin)*/){
  int tile   = idx >> 9;
  int within = idx & 511;
  int ot  = tile >> s;
  int k32 = tile & ((1<<s)-1);
  int kk   = within & 31;
  int orow = within >> 5;
  int o = ot*16 + orow;
  int k = k32*32 + kk;
  int m = k >> cb;
  int i = k & (cin-1);
  Bt[idx] = f2b(w2[(size_t)m*(cin*64) + i*64 + o]);
}

__global__ __launch_bounds__(256) void k_prep(
    const float* __restrict__ w2a, unsigned short* __restrict__ Bt1,
    const float* __restrict__ w2b, unsigned short* __restrict__ Bt2,
    int* __restrict__ cnt){
  int b = blockIdx.x;
  int t = threadIdx.x;
  if(b < 40){
    int i = b*256 + t;
    if(i < NN) cnt[i] = 0;
  } else if(b < 296){
    do_permB((b-40)*256 + t, w2a, Bt1, 16, 5, 4);
  } else {
    do_permB((b-296)*256 + t, w2b, Bt2, 64, 7, 6);
  }
}

// ---------------- CSR build ----------------

__global__ void k_hist(const int* __restrict__ dst, int* __restrict__ cnt){
  int e = blockIdx.x*256 + threadIdx.x;
  if(e < EE) atomicAdd(&cnt[dst[e]], 1);
}

__global__ __launch_bounds__(1024) void k_scan(const int* __restrict__ cnt, int* __restrict__ offs, int* __restrict__ cursor){
  const int T = 1024, PER = (NN + T - 1)/T; // 10
  int tid = threadIdx.x;
  int base = tid*PER;
  int local[PER];
  int s = 0;
  #pragma unroll
  for(int j=0;j<PER;j++){
    int i = base+j;
    int v = (i<NN)? cnt[i] : 0;
    local[j] = s;
    s += v;
  }
  int lane = tid & 63, wv = tid >> 6;
  int val = s;
  #pragma unroll
  for(int o=1;o<64;o<<=1){
    int u = __shfl_up(val, o, 64);
    if(lane >= o) val += u;
  }
  __shared__ int wsum[16];
  if(lane==63) wsum[wv] = val;
  __syncthreads();
  if(tid==0){
    int acc=0;
    #pragma unroll
    for(int i=0;i<16;i++){ int t2=wsum[i]; wsum[i]=acc; acc+=t2; }
  }
  __syncthreads();
  int thr_excl = wsum[wv] + (val - s);
  #pragma unroll
  for(int j=0;j<PER;j++){
    int i = base+j;
    if(i<NN){ int e = thr_excl + local[j]; offs[i]=e; cursor[i]=e; }
  }
  if(tid == T-1) offs[NN] = thr_excl + s;
}

__global__ void k_scatter(const int* __restrict__ dst, const int* __restrict__ src,
                          int* __restrict__ cursor, int2* __restrict__ elist2){
  int e = blockIdx.x*256 + threadIdx.x;
  if(e < EE){ int p = atomicAdd(&cursor[dst[e]], 1); elist2[p] = make_int2(e, src[e]); }
}

// ---------------- per-dst rank-1 accumulation + inline edge-MLP, cin=16 ----------------

__global__ __launch_bounds__(64) void k_accK1(const float* __restrict__ x,
    const int* __restrict__ offs, const int2* __restrict__ elist2,
    const float* __restrict__ ea, const float* __restrict__ w1, const float* __restrict__ b1,
    unsigned short* __restrict__ K1, float* __restrict__ XS, int v0){
  int v = v0 + blockIdx.x;
  int L = threadIdx.x;
  int cg = L & 3, mg = L >> 2;
  int i0 = cg << 2;
  float w1c0 = w1[L], w1c1 = w1[64+L], w1c2 = w1[128+L], w1c3 = w1[192+L];
  float b1c = b1[L];
  __shared__ float sh[2][64];
  float acc[4][4];
  #pragma unroll
  for(int j=0;j<4;j++)
    #pragma unroll
    for(int c=0;c<4;c++) acc[j][c]=0.f;
  float4 xs = make_float4(0.f,0.f,0.f,0.f);
  int p0 = offs[v], p1 = offs[v+1];
  float4 a_nxt = make_float4(0.f,0.f,0.f,0.f);
  float4 x_nxt = make_float4(0.f,0.f,0.f,0.f);
  if(p0 < p1){
    int2 es = elist2[p0];
    a_nxt = *(const float4*)(ea + (size_t)es.x*4);
    x_nxt = *(const float4*)(x + (size_t)es.y*16 + i0);
  }
  for(int p=p0;p<p1;p++){
    int buf = (p-p0)&1;
    float4 xv = x_nxt;
    float4 av = a_nxt;
    float hv = fmaxf(b1c + av.x*w1c0 + av.y*w1c1 + av.z*w1c2 + av.w*w1c3, 0.f);
    sh[buf][L] = hv;
    __syncthreads();
    if(p+1<p1){
      int2 es = elist2[p+1];
      a_nxt = *(const float4*)(ea + (size_t)es.x*4);
      x_nxt = *(const float4*)(x + (size_t)es.y*16 + i0);
    }
    xs.x += xv.x; xs.y += xv.y; xs.z += xv.z; xs.w += xv.w;
    #pragma unroll
    for(int j=0;j<4;j++){
      float hm = sh[buf][mg + 16*j];
      acc[j][0] += hm*xv.x; acc[j][1] += hm*xv.y;
      acc[j][2] += hm*xv.z; acc[j][3] += hm*xv.w;
    }
  }
  int r = blockIdx.x;
  int rt = r >> 4, lrow = r & 15;
  #pragma unroll
  for(int j=0;j<4;j++){
    int m = mg + 16*j;
    size_t sidx = ((size_t)(rt*32 + (m>>1)))*512
                + (size_t)lrow*32 + (m&1)*16 + cg*4;
    ushort4 u;
    u.x=f2b(acc[j][0]); u.y=f2b(acc[j][1]); u.z=f2b(acc[j][2]); u.w=f2b(acc[j][3]);
    *(ushort4*)(K1 + sidx) = u;
  }
  if(mg==0) *(float4*)(XS + (size_t)v*64 + i0) = xs;
}

// ---------------- per-dst rank-1 accumulation + inline edge-MLP, cin=64 ----------------

__global__ __launch_bounds__(64) void k_accK2(const float* __restrict__ x1,
    const int* __restrict__ offs, const int2* __restrict__ elist2,
    const float* __restrict__ ea, const float* __restrict__ w1, const float* __restrict__ b1,
    unsigned short* __restrict__ K, float* __restrict__ XS, int v0){
  int v = v0 + blockIdx.x;
  int L = threadIdx.x;
  int cg = L & 7, mg = L >> 3;
  int i0 = cg << 3;
  float w1c0 = w1[L], w1c1 = w1[64+L], w1c2 = w1[128+L], w1c3 = w1[192+L];
  float b1c = b1[L];
  __shared__ float sh[2][64];
  float acc[8][8];
  #pragma unroll
  for(int j=0;j<8;j++)
    #pragma unroll
    for(int c=0;c<8;c++) acc[j][c]=0.f;
  float4 xs0 = make_float4(0.f,0.f,0.f,0.f);
  float4 xs1 = make_float4(0.f,0.f,0.f,0.f);
  int p0 = offs[v], p1 = offs[v+1];
  float4 a_nxt = make_float4(0.f,0.f,0.f,0.f);
  float4 x_nxt0 = make_float4(0.f,0.f,0.f,0.f);
  float4 x_nxt1 = make_float4(0.f,0.f,0.f,0.f);
  if(p0 < p1){
    int2 es = elist2[p0];
    a_nxt = *(const float4*)(ea + (size_t)es.x*4);
    const float* xr = x1 + (size_t)es.y*64 + i0;
    x_nxt0 = *(const float4*)xr;
    x_nxt1 = *(const float4*)(xr+4);
  }
  for(int p=p0;p<p1;p++){
    int buf = (p-p0)&1;
    float4 xv0 = x_nxt0, xv1 = x_nxt1;
    float4 av = a_nxt;
    float hv = fmaxf(b1c + av.x*w1c0 + av.y*w1c1 + av.z*w1c2 + av.w*w1c3, 0.f);
    sh[buf][L] = hv;
    __syncthreads();
    if(p+1<p1){
      int2 es = elist2[p+1];
      a_nxt = *(const float4*)(ea + (size_t)es.x*4);
      const float* xr = x1 + (size_t)es.y*64 + i0;
      x_nxt0 = *(const float4*)xr;
      x_nxt1 = *(const float4*)(xr+4);
    }
    xs0.x += xv0.x; xs0.y += xv0.y; xs0.z += xv0.z; xs0.w += xv0.w;
    xs1.x += xv1.x; xs1.y += xv1.y; xs1.z += xv1.z; xs1.w += xv1.w;
    float4 h4a = *(float4*)&sh[buf][mg*8];
    float4 h4b = *(float4*)&sh[buf][mg*8+4];
    #pragma unroll
    for(int jj=0;jj<2;jj++){
      float4 h4 = jj? h4b : h4a;
      #pragma unroll
      for(int tq=0;tq<4;tq++){
        int j = jj*4+tq;
        float hm = (tq==0)?h4.x:(tq==1)?h4.y:(tq==2)?h4.z:h4.w;
        acc[j][0] += hm*xv0.x; acc[j][1] += hm*xv0.y;
        acc[j][2] += hm*xv0.z; acc[j][3] += hm*xv0.w;
        acc[j][4] += hm*xv1.x; acc[j][5] += hm*xv1.y;
        acc[j][6] += hm*xv1.z; acc[j][7] += hm*xv1.w;
      }
    }
  }
  int r = blockIdx.x;
  int rt = r >> 4, lrow = r & 15;
  #pragma unroll
  for(int j=0;j<8;j++){
    int m = mg*8 + j;
    size_t sidx = ((size_t)(rt*128 + m*2 + (cg>>2)))*512
                + (size_t)lrow*32 + (cg&3)*8;
    u16x8 u;
    #pragma unroll
    for(int c=0;c<8;c++) u[c] = f2b(acc[j][c]);
    *(u16x8*)(K + sidx) = u;
  }
  if(mg==0){
    *(float4*)(XS + (size_t)v*64 + i0)     = xs0;
    *(float4*)(XS + (size_t)v*64 + i0 + 4) = xs1;
  }
}

// ---------------- split-K GEMM, 128 rows/block, B-slice staged in LDS ----------------
// 512 thr = 8 waves; wave w owns row-tile blockIdx.x*8+w (16 rows), all 64 cols,
// K-range = [blockIdx.y*TSTEPS*32, +TSTEPS*32). B-slice (4*TSTEPS KB) staged to LDS
// once and shared by all 8 waves -> B global traffic = (NN/128)*Bt_bytes, 8x less
// than 16-row blocks. A streamed nt (read-once). Output: P[s][row][col] (f32).

template<int KT32, int TSTEPS>
__global__ __launch_bounds__(512) void k_gemmS(const unsigned short* __restrict__ A,
    const unsigned short* __restrict__ Bt, float* __restrict__ P,
    int ntiles, int rowsChunk){
  __shared__ unsigned short Bs[4*TSTEPS*512];
  int tid = threadIdx.x;
  int lane = tid & 63;
  int w = tid >> 6;
  int s = blockIdx.y;
  int kbase = s*TSTEPS;

  // stage B slice: 4*TSTEPS tiles of 1KB, spread over 8 waves
  constexpr int NT = 4*TSTEPS;
  constexpr int PERW = NT/8;
  #pragma unroll
  for(int it=0; it<PERW; it++){
    int g = w*PERW + it;
    int ct = g / TSTEPS, t = g - ct*TSTEPS;
    *(short8*)(Bs + (size_t)g*512 + lane*8) =
        *(const short8*)(Bt + (((size_t)ct*KT32 + kbase + t) << 9) + lane*8);
  }
  __syncthreads();

  int lrt = blockIdx.x*8 + w;
  if(lrt >= ntiles) return;   // after the only barrier -> safe

  int lperm = (lane & 15)*32 + (lane >> 4)*8;
  const unsigned short* Ap = A + (((size_t)lrt*KT32 + kbase) << 9) + lperm;
  const unsigned short* BsL = Bs + lperm;

  float4v acc0{}, acc1{}, acc2{}, acc3{};
  short8 ab[4];
  #pragma unroll
  for(int t=0;t<4;t++) ab[t] = ntload(Ap + t*512);

  #pragma unroll
  for(int t=0;t<TSTEPS;t++){
    short8 a  = ab[t&3];
    short8 b0 = *(const short8*)(BsL + (0*TSTEPS+t)*512);
    short8 b1 = *(const short8*)(BsL + (1*TSTEPS+t)*512);
    short8 b2 = *(const short8*)(BsL + (2*TSTEPS+t)*512);
    short8 b3 = *(const short8*)(BsL + (3*TSTEPS+t)*512);
    acc0 = __builtin_amdgcn_mfma_f32_16x16x32_bf16(a, b0, acc0, 0,0,0);
    acc1 = __builtin_amdgcn_mfma_f32_16x16x32_bf16(a, b1, acc1, 0,0,0);
    acc2 = __builtin_amdgcn_mfma_f32_16x16x32_bf16(a, b2, acc2, 0,0,0);
    acc3 = __builtin_amdgcn_mfma_f32_16x16x32_bf16(a, b3, acc3, 0,0,0);
    if(t+4 < TSTEPS) ab[t&3] = ntload(Ap + (t+4)*512);
  }

  int lrow = lane & 15, quad = lane >> 4;
  float* Pr = P + ((size_t)s*rowsChunk + lrt*16 + quad*4)*64 + lrow;
  #pragma unroll
  for(int reg=0;reg<4;reg++){
    Pr[(size_t)reg*64 +  0] = acc0[reg];
    Pr[(size_t)reg*64 + 16] = acc1[reg];
    Pr[(size_t)reg*64 + 32] = acc2[reg];
    Pr[(size_t)reg*64 + 48] = acc3[reg];
  }
}

// ---------------- split reduction + epilogue (layer1) ----------------

template<int CIN, int SPLIT>
__global__ __launch_bounds__(256) void k_reduce_ep(const float* __restrict__ P, int rows, int v0,
    const float* __restrict__ XS, const float* __restrict__ b2, const float* __restrict__ xprev,
    const float* __restrict__ root, const float* __restrict__ bias, const int* __restrict__ offs,
    float* __restrict__ out){
  int idx = blockIdx.x*256 + threadIdx.x;
  if(idx >= rows*16) return;
  int r = idx >> 4, og = (idx & 15) << 2;
  int v = v0 + r;

  float4 s = make_float4(0.f,0.f,0.f,0.f);
  #pragma unroll
  for(int z=0; z<SPLIT; z++){
    float4 p = *(const float4*)(P + ((size_t)z*rows + r)*64 + og);
    s.x += p.x; s.y += p.y; s.z += p.z; s.w += p.w;
  }
  #pragma unroll
  for(int i=0;i<CIN;i++){
    float xsv = XS[(size_t)v*64 + i];
    float4 b = *(const float4*)(b2 + i*64 + og);
    s.x += xsv*b.x; s.y += xsv*b.y; s.z += xsv*b.z; s.w += xsv*b.w;
  }
  float4 rt = make_float4(0.f,0.f,0.f,0.f);
  #pragma unroll
  for(int i=0;i<CIN;i++){
    float xv = xprev[(size_t)v*CIN + i];
    float4 wv = *(const float4*)(root + i*64 + og);
    rt.x += xv*wv.x; rt.y += xv*wv.y; rt.z += xv*wv.z; rt.w += xv*wv.w;
  }
  float c = (float)(offs[v+1]-offs[v]); c = fmaxf(c, 1.f);
  float inv = 1.f/c;
  float4 bi = *(const float4*)(bias + og);
  float4 o;
  o.x = fmaxf(s.x*inv + rt.x + bi.x, 0.f);
  o.y = fmaxf(s.y*inv + rt.y + bi.y, 0.f);
  o.z = fmaxf(s.z*inv + rt.z + bi.z, 0.f);
  o.w = fmaxf(s.w*inv + rt.w + bi.w, 0.f);
  *(float4*)(out + (size_t)v*64 + og) = o;
}

// ---------------- layer-2 reduction + epilogue + fused readout ----------------

template<int SPLIT>
__global__ __launch_bounds__(256) void k_red2_ro(const float* __restrict__ P, int rows, int v0,
    const float* __restrict__ XS, const float* __restrict__ b2, const float* __restrict__ x1,
    const float* __restrict__ root, const float* __restrict__ bias, const int* __restrict__ offs,
    const float* __restrict__ lw1, const float* __restrict__ lb1,
    const float* __restrict__ lw2, const float* __restrict__ lb2,
    float* __restrict__ out){
  __shared__ float row[16][68];
  __shared__ float hjs[16][8];
  int tid = threadIdx.x;
  int idx = blockIdx.x*256 + tid;
  int r = idx >> 4, og = (idx & 15) << 2;
  int n = tid >> 4;
  int nbase = blockIdx.x*16;
  int ninblk = rows - nbase; if(ninblk > 16) ninblk = 16;

  float4 o = make_float4(0.f,0.f,0.f,0.f);
  if(r < rows){
    int vg = v0 + r;
    float4 s = make_float4(0.f,0.f,0.f,0.f);
    #pragma unroll
    for(int z=0; z<SPLIT; z++){
      float4 p = *(const float4*)(P + ((size_t)z*rows + r)*64 + og);
      s.x += p.x; s.y += p.y; s.z += p.z; s.w += p.w;
    }
    #pragma unroll
    for(int i=0;i<64;i++){
      float xsv = XS[(size_t)vg*64 + i];
      float4 b = *(const float4*)(b2 + i*64 + og);
      s.x += xsv*b.x; s.y += xsv*b.y; s.z += xsv*b.z; s.w += xsv*b.w;
    }
    float4 rt = make_float4(0.f,0.f,0.f,0.f);
    #pragma unroll
    for(int i=0;i<64;i++){
      float xv = x1[(size_t)vg*64 + i];
      float4 wv = *(const float4*)(root + i*64 + og);
      rt.x += xv*wv.x; rt.y += xv*wv.y; rt.z += xv*wv.z; rt.w += xv*wv.w;
    }
    float c = (float)(offs[vg+1]-offs[vg]); c = fmaxf(c, 1.f);
    float inv = 1.f/c;
    float4 bi = *(const float4*)(bias + og);
    o.x = fmaxf(s.x*inv + rt.x + bi.x, 0.f);
    o.y = fmaxf(s.y*inv + rt.y + bi.y, 0.f);
    o.z = fmaxf(s.z*inv + rt.z + bi.z, 0.f);
    o.w = fmaxf(s.w*inv + rt.w + bi.w, 0.f);
  }
  *(float4*)&row[n][og] = o;
  __syncthreads();
  if(tid < 128){
    int n2 = tid >> 3, j = tid & 7;
    if(n2 < ninblk){
      float a = lb1[j];
      #pragma unroll
      for(int i=0;i<64;i++) a += row[n2][i]*lw1[i*8+j];
      hjs[n2][j] = fmaxf(a, 0.f)*lw2[j];
    }
  }
  __syncthreads();
  if(tid < 16 && tid < ninblk){
    float s = lb2[0];
    #pragma unroll
    for(int j=0;j<8;j++) s += hjs[tid][j];
    out[v0 + nbase + tid] = s;
  }
}

// ---------------- host ----------------

extern "C" void kernel_launch(void* const* d_in, const int* in_sizes, int n_in,
                              void* d_out, int out_size, void* d_ws, size_t ws_size,
                              hipStream_t stream) {
  const float* x      = (const float*)d_in[0];
  const int*   ei     = (const int*)d_in[1];
  const float* ea     = (const float*)d_in[2];
  const float* nn1_w1 = (const float*)d_in[3];
  const float* nn1_b1 = (const float*)d_in[4];
  const float* nn1_w2 = (const float*)d_in[5];
  const float* nn1_b2 = (const float*)d_in[6];
  const float* root1  = (const float*)d_in[7];
  const float* bias1  = (const float*)d_in[8];
  const float* nn2_w1 = (const float*)d_in[9];
  const float* nn2_b1 = (const float*)d_in[10];
  const float* nn2_w2 = (const float*)d_in[11];
  const float* nn2_b2 = (const float*)d_in[12];
  const float* root2  = (const float*)d_in[13];
  const float* bias2  = (const float*)d_in[14];
  const float* lin1_w = (const float*)d_in[15];
  const float* lin1_b = (const float*)d_in[16];
  const float* lin2_w = (const float*)d_in[17];
  const float* lin2_b = (const float*)d_in[18];
  float* out = (float*)d_out;

  const int* srcIdx = ei;
  const int* dstIdx = ei + EE;

  char* w = (char*)d_ws;
  size_t off = 0;
  auto alloc = [&](size_t bytes)->void*{
    void* p = w + off;
    off = (off + bytes + 255) & ~(size_t)255;
    return p;
  };
  int*            cnt    = (int*)           alloc((size_t)NN*4);
  int*            offs   = (int*)           alloc((size_t)(NN+1)*4);
  int*            cursor = (int*)           alloc((size_t)NN*4);
  int2*           elist2 = (int2*)          alloc((size_t)EE*8);
  float*          XS     = (float*)         alloc((size_t)NN*64*4);
  float*          x1     = (float*)         alloc((size_t)NN*64*4);
  unsigned short* Bt1    = (unsigned short*)alloc((size_t)64*1024*2);
  unsigned short* Bt2    = (unsigned short*)alloc((size_t)64*4096*2);
  size_t fixedBytes = off;
  size_t R = (ws_size > fixedBytes) ? (ws_size - fixedBytes) : 0;

  const int S1 = 4, S2 = 8;
  // layer1: KT32=32,  TSTEPS=32/S1 = 8   (B-slice 32KB LDS)
  // layer2: KT32=128, TSTEPS=128/S2 = 16 (B-slice 64KB LDS)
  size_t needSingle = (size_t)(NN/16)*128*1024 + (size_t)S2*NN*64*4;
  bool single = (R >= needSingle + 4096);

  k_prep   <<<1320, 256, 0, stream>>>(nn1_w2, Bt1, nn2_w2, Bt2, cnt);
  k_hist   <<<(EE+255)/256, 256, 0, stream>>>(dstIdx, cnt);
  k_scan   <<<1, 1024, 0, stream>>>(cnt, offs, cursor);
  k_scatter<<<(EE+255)/256, 256, 0, stream>>>(dstIdx, srcIdx, cursor, elist2);

  if(single){
    unsigned short* Kbuf = (unsigned short*)(w + off);
    float* P = (float*)(w + off + (size_t)(NN/16)*128*1024);
    int ntiles = NN/16;                 // 625
    int gx = (ntiles + 7)/8;            // 79

    k_accK1 <<<NN, 64, 0, stream>>>(x, offs, elist2, ea, nn1_w1, nn1_b1, Kbuf, XS, 0);
    k_gemmS<32,8> <<<dim3(gx, S1), 512, 0, stream>>>(Kbuf, Bt1, P, ntiles, NN);
    k_reduce_ep<16,S1><<<(NN*16+255)/256, 256, 0, stream>>>(P, NN, 0, XS, nn1_b2, x,
                                                             root1, bias1, offs, x1);
    k_accK2 <<<NN, 64, 0, stream>>>(x1, offs, elist2, ea, nn2_w1, nn2_b1, Kbuf, XS, 0);
    k_gemmS<128,16><<<dim3(gx, S2), 512, 0, stream>>>(Kbuf, Bt2, P, ntiles, NN);
    k_red2_ro<S2><<<(NN+15)/16, 256, 0, stream>>>(P, NN, 0, XS, nn2_b2, x1, root2, bias2, offs,
                                                   lin1_w, lin1_b, lin2_w, lin2_b, out);
  } else {
    // chunked fallback: per-row bytes layer2 = 8KB(K) + S2*256B(P) = 10KB; layer1 = 2KB + 1KB
    long long C2 = (long long)(R / (8192 + S2*256));
    long long C1 = (long long)(R / (2048 + S1*256));
    if(C2 > NN) C2 = NN; if(C1 > NN) C1 = NN;
    C2 &= ~127LL; C1 &= ~127LL;
    if(C2 < 128) C2 = 128; if(C1 < 128) C1 = 128;
    unsigned short* Kbuf = (unsigned short*)(w + off);
    {
      float* P = (float*)(w + off + (size_t)C1*2048);
      for(long long v0=0; v0<NN; v0+=C1){
        int rows = (int)((NN - v0 < C1) ? (NN - v0) : C1);
        int nt = rows/16, gx = (nt + 7)/8;
        k_accK1<<<rows, 64, 0, stream>>>(x, offs, elist2, ea, nn1_w1, nn1_b1, Kbuf, XS, (int)v0);
        k_gemmS<32,8><<<dim3(gx, S1), 512, 0, stream>>>(Kbuf, Bt1, P, nt, rows);
        k_reduce_ep<16,S1><<<(rows*16+255)/256, 256, 0, stream>>>(P, rows, (int)v0, XS, nn1_b2, x,
                                                                   root1, bias1, offs, x1);
      }
    }
    {
      float* P = (float*)(w + off + (size_t)C2*8192);
      for(long long v0=0; v0<NN; v0+=C2){
        int rows = (int)((NN - v0 < C2) ? (NN - v0) : C2);
        int nt = rows/16, gx = (nt + 7)/8;
        k_accK2<<<rows, 64, 0, stream>>>(x1, offs, elist2, ea, nn2_w1, nn2_b1, Kbuf, XS, (int)v0);
        k_gemmS<128,16><<<dim3(gx, S2), 512, 0, stream>>>(Kbuf, Bt2, P, nt, rows);
        k_red2_ro<S2><<<(rows+15)/16, 256, 0, stream>>>(P, rows, (int)v0, XS, nn2_b2, x1,
                                                         root2, bias2, offs,
                                                         lin1_w, lin1_b, lin2_w, lin2_b, out);
      }
    }
  }
}